// Round 10
// baseline (350.200 us; speedup 1.0000x reference)
//
#include <hip/hip_runtime.h>

typedef unsigned short u16;
typedef unsigned int   u32;
typedef float f32x4 __attribute__((ext_vector_type(4)));
typedef __bf16 bf16x8 __attribute__((ext_vector_type(8)));
typedef unsigned short u16x8 __attribute__((ext_vector_type(8)));

#define PP   6400
#define HH   80
#define WW   80
#define KC   256
#define CH   324
#define CPAD 384
#define PW   82          // padded spatial width
#define PPIX (PW*PW)     // 6724 padded pixels
#define NPOOL 2176       // pooled cells padded (1600+400+100 -> 2176)

__device__ inline float b2f(u16 u) { union { u32 i; float f; } v; v.i = ((u32)u) << 16; return v.f; }
__device__ inline u16 f2b(float f) {
    union { u32 i; float f; } v; v.f = f;
    u32 r = v.i + 0x7fffu + ((v.i >> 16) & 1u);
    return (u16)(r >> 16);
}

// async global->LDS, 16B per lane; LDS dst = wave-uniform base + lane*16
__device__ __forceinline__ void gload16(const void* g, void* l) {
    __builtin_amdgcn_global_load_lds((const __attribute__((address_space(1))) void*)g,
                                     (__attribute__((address_space(3))) void*)l, 16, 0, 0);
}

// ---------------- prep: fA[p][c] = bf16(f[c][p]) via LDS tile transpose ----------------
__global__ __launch_bounds__(256) void prep_f(const float* __restrict__ f0,
                                              const float* __restrict__ f1,
                                              u16* __restrict__ fA, u16* __restrict__ fB) {
    __shared__ float tile[64][65];
    int p0 = blockIdx.x * 64, c0 = blockIdx.y * 64;
    const float* src = blockIdx.z ? f1 : f0;
    u16* dst = blockIdx.z ? fB : fA;
    int tid = threadIdx.x;
#pragma unroll
    for (int it = 0; it < 16; ++it) {
        int idx = tid + it * 256;
        int cc = idx >> 6, pp = idx & 63;
        tile[cc][pp] = src[(size_t)(c0 + cc) * PP + p0 + pp];
    }
    __syncthreads();
#pragma unroll
    for (int it = 0; it < 16; ++it) {
        int idx = tid + it * 256;
        int pp = idx >> 6, cc = idx & 63;
        dst[(size_t)(p0 + pp) * KC + c0 + cc] = f2b(tile[cc][pp]);
    }
}

// ---------------- prep weights (coalesced tile transpose): wT[tap][co][ci] ----------------
__global__ __launch_bounds__(256) void prep_w(const float* __restrict__ w1,
                                              const float* __restrict__ w2,
                                              u16* __restrict__ wT1, u16* __restrict__ wT2) {
    __shared__ float tile[64][65];
    int tap = blockIdx.x;                 // 0..8
    int t6 = blockIdx.y;                  // 0..35
    int ci0 = (t6 / 6) * 64, co0 = (t6 % 6) * 64;
    const float* w = blockIdx.z ? w2 : w1;
    u16* wT = blockIdx.z ? wT2 : wT1;
    int tid = threadIdx.x;
#pragma unroll
    for (int it = 0; it < 16; ++it) {
        int idx = tid + it * 256;
        int ciL = idx >> 6, coL = idx & 63;
        int ci = ci0 + ciL, co = co0 + coL;
        tile[ciL][coL] = (ci < CH && co < CH) ? w[((size_t)tap * CH + ci) * CH + co] : 0.f;
    }
    __syncthreads();
#pragma unroll
    for (int it = 0; it < 16; ++it) {
        int idx = tid + it * 256;
        int coL = idx >> 6, ciL = idx & 63;
        wT[((size_t)tap * CPAD + co0 + coL) * CPAD + ci0 + ciL] = f2b(tile[ciL][coL]);
    }
}

__global__ __launch_bounds__(384) void prep_b(const float* __restrict__ b1,
                                              const float* __restrict__ b2,
                                              float* __restrict__ b1p, float* __restrict__ b2p) {
    int t = threadIdx.x;
    b1p[t] = t < CH ? b1[t] : 0.f;
    b2p[t] = t < CH ? b2[t] : 0.f;
}

// ---------------- zero the 1-pixel halo of feat and t1 (ws is re-poisoned every call) ----------------
__global__ __launch_bounds__(384) void zero_border(u16* __restrict__ feat, u16* __restrict__ t1) {
    int bi = blockIdx.x, dir = blockIdx.y;
    int pix;
    if (bi < 82) pix = bi;                        // top row
    else if (bi < 164) pix = 81 * PW + (bi - 82); // bottom row
    else if (bi < 244) pix = (bi - 164 + 1) * PW; // left col
    else pix = (bi - 244 + 1) * PW + 81;          // right col
    size_t off = ((size_t)dir * PPIX + pix) * CPAD + threadIdx.x;
    feat[off] = 0;
    t1[off] = 0;
}

// ---------------- pooled features, hierarchical: L1(1600)+L2(400)+L3(100) in one pass ----------------
__global__ __launch_bounds__(256) void pool_feat(const u16* __restrict__ fA,
                                                 const u16* __restrict__ fB,
                                                 u16* __restrict__ pbarA,
                                                 u16* __restrict__ pbarB) {
    int j = blockIdx.x;                       // L3 cell 0..99
    const u16* src = blockIdx.y ? fA : fB;    // y=0: pooled B (for dir0), y=1: pooled A (for dir1)
    u16* dst = blockIdx.y ? pbarA : pbarB;
    int k = threadIdx.x;
    int cy3 = j / 10, cx3 = j % 10;
    float l1v[16], l2v[4];
#pragma unroll
    for (int a = 0; a < 4; ++a)
#pragma unroll
        for (int b = 0; b < 4; ++b) {
            int cy = cy3 * 4 + a, cx = cx3 * 4 + b;
            int p00 = (2 * cy) * 80 + 2 * cx;
            float v = 0.25f * (b2f(src[(size_t)p00 * KC + k]) + b2f(src[(size_t)(p00 + 1) * KC + k]) +
                               b2f(src[(size_t)(p00 + 80) * KC + k]) + b2f(src[(size_t)(p00 + 81) * KC + k]));
            l1v[a * 4 + b] = v;
            dst[(size_t)(cy * 40 + cx) * KC + k] = f2b(v);
        }
#pragma unroll
    for (int a = 0; a < 2; ++a)
#pragma unroll
        for (int b = 0; b < 2; ++b) {
            float v = 0.25f * (l1v[(2 * a) * 4 + 2 * b] + l1v[(2 * a) * 4 + 2 * b + 1] +
                               l1v[(2 * a + 1) * 4 + 2 * b] + l1v[(2 * a + 1) * 4 + 2 * b + 1]);
            l2v[a * 2 + b] = v;
            dst[(size_t)(1600 + (cy3 * 2 + a) * 20 + cx3 * 2 + b) * KC + k] = f2b(v);
        }
    float v3 = 0.25f * (l2v[0] + l2v[1] + l2v[2] + l2v[3]);
    dst[(size_t)(2000 + j) * KC + k] = f2b(v3);
}

// ---------------- banded corr GEMM: only diagonal-band 128x128 tiles (|p-q|<=324) ----------------
__global__ __launch_bounds__(256) void gemm_band(const u16* __restrict__ fA,
                                                 const u16* __restrict__ fB,
                                                 u16* __restrict__ corr01,
                                                 u16* __restrict__ corr10) {
    int n0t = (int)blockIdx.x + (int)blockIdx.y - 3;
    if (n0t < 0 || n0t >= 50) return;
    __shared__ __align__(16) char smem[128 * 136 * 2];   // As+Bs (32KB) overlap trans (34KB)
    u16* As = (u16*)smem;
    u16* Bs = As + 128 * 64;
    u16* trans = (u16*)smem;
    const int TS = 136;
    int tid = threadIdx.x;
    int wave = tid >> 6, lane = tid & 63;
    int quad = lane >> 4, l16 = lane & 15;
    int lrow = lane >> 3, lchunk = lane & 7;
    int sc = lchunk ^ (lrow & 7);
    int sw = l16 & 7;
    int wr = (wave >> 1) * 64, wc = (wave & 1) * 64;
    int m0 = blockIdx.x * 128, n0 = n0t * 128;
    f32x4 acc[4][4] = {};

    for (int k0 = 0; k0 < KC; k0 += 64) {
        __syncthreads();
#pragma unroll
        for (int i = 0; i < 4; ++i) {
            int row = i * 32 + wave * 8 + lrow;
            gload16(&fA[(size_t)(m0 + row) * KC + k0 + sc * 8], &As[(i * 32 + wave * 8) * 64]);
            gload16(&fB[(size_t)(n0 + row) * KC + k0 + sc * 8], &Bs[(i * 32 + wave * 8) * 64]);
        }
        __syncthreads();
#pragma unroll
        for (int ki = 0; ki < 2; ++ki) {
            bf16x8 af[4], bfr[4];
#pragma unroll
            for (int mi = 0; mi < 4; ++mi) {
                int r = wr + mi * 16 + l16;
                af[mi] = *(const bf16x8*)(&As[r * 64 + (((ki * 4 + quad) ^ sw) * 8)]);
            }
#pragma unroll
            for (int ni = 0; ni < 4; ++ni) {
                int r = wc + ni * 16 + l16;
                bfr[ni] = *(const bf16x8*)(&Bs[r * 64 + (((ki * 4 + quad) ^ sw) * 8)]);
            }
#pragma unroll
            for (int mi = 0; mi < 4; ++mi)
#pragma unroll
                for (int ni = 0; ni < 4; ++ni)
                    acc[mi][ni] = __builtin_amdgcn_mfma_f32_16x16x32_bf16(af[mi], bfr[ni], acc[mi][ni], 0, 0, 0);
        }
    }
#pragma unroll
    for (int mi = 0; mi < 4; ++mi)
#pragma unroll
        for (int ni = 0; ni < 4; ++ni)
#pragma unroll
            for (int rr = 0; rr < 4; ++rr) {
                int row = m0 + wr + mi * 16 + quad * 4 + rr;
                int col = n0 + wc + ni * 16 + l16;
                corr01[(size_t)row * PP + col] = f2b(acc[mi][ni][rr]);
            }
    __syncthreads();
#pragma unroll
    for (int mi = 0; mi < 4; ++mi)
#pragma unroll
        for (int ni = 0; ni < 4; ++ni) {
            int c = wc + ni * 16 + l16;
            int rbase = wr + mi * 16 + quad * 4;
#pragma unroll
            for (int h = 0; h < 2; ++h) {
                u32 pk = (u32)f2b(acc[mi][ni][2 * h]) | ((u32)f2b(acc[mi][ni][2 * h + 1]) << 16);
                *(u32*)(&trans[c * TS + rbase + 2 * h]) = pk;
            }
        }
    __syncthreads();
#pragma unroll
    for (int it = 0; it < 8; ++it) {
        int c = it * 16 + (tid >> 4);
        int r8 = (tid & 15) * 8;
        u16x8 v = *(const u16x8*)(&trans[c * TS + r8]);
        *(u16x8*)(&corr10[(size_t)(n0 + c) * PP + m0 + r8]) = v;
    }
}

// ---------------- pooled-corr GEMM: pc[dir][p][cell] = A[p] . pbar[cell], N=2176 ----------------
__global__ __launch_bounds__(256) void gemm_pool(const u16* __restrict__ fA,
                                                 const u16* __restrict__ fB,
                                                 const u16* __restrict__ pbarA,
                                                 const u16* __restrict__ pbarB,
                                                 u16* __restrict__ pc) {
    int dir = blockIdx.z;
    const u16* A = dir ? fB : fA;
    const u16* Bp = dir ? pbarA : pbarB;
    __shared__ __align__(16) u16 As[128 * 64];
    __shared__ __align__(16) u16 Bs[128 * 64];
    int tid = threadIdx.x;
    int wave = tid >> 6, lane = tid & 63;
    int quad = lane >> 4, l16 = lane & 15;
    int lrow = lane >> 3, lchunk = lane & 7;
    int sc = lchunk ^ (lrow & 7);
    int sw = l16 & 7;
    int wr = (wave >> 1) * 64, wc = (wave & 1) * 64;
    int m0 = blockIdx.x * 128, n0 = blockIdx.y * 128;
    f32x4 acc[4][4] = {};

    for (int k0 = 0; k0 < KC; k0 += 64) {
        __syncthreads();
#pragma unroll
        for (int i = 0; i < 4; ++i) {
            int row = i * 32 + wave * 8 + lrow;
            gload16(&A[(size_t)(m0 + row) * KC + k0 + sc * 8], &As[(i * 32 + wave * 8) * 64]);
            gload16(&Bp[(size_t)(n0 + row) * KC + k0 + sc * 8], &Bs[(i * 32 + wave * 8) * 64]);
        }
        __syncthreads();
#pragma unroll
        for (int ki = 0; ki < 2; ++ki) {
            bf16x8 af[4], bfr[4];
#pragma unroll
            for (int mi = 0; mi < 4; ++mi) {
                int r = wr + mi * 16 + l16;
                af[mi] = *(const bf16x8*)(&As[r * 64 + (((ki * 4 + quad) ^ sw) * 8)]);
            }
#pragma unroll
            for (int ni = 0; ni < 4; ++ni) {
                int r = wc + ni * 16 + l16;
                bfr[ni] = *(const bf16x8*)(&Bs[r * 64 + (((ki * 4 + quad) ^ sw) * 8)]);
            }
#pragma unroll
            for (int mi = 0; mi < 4; ++mi)
#pragma unroll
                for (int ni = 0; ni < 4; ++ni)
                    acc[mi][ni] = __builtin_amdgcn_mfma_f32_16x16x32_bf16(af[mi], bfr[ni], acc[mi][ni], 0, 0, 0);
        }
    }
#pragma unroll
    for (int mi = 0; mi < 4; ++mi)
#pragma unroll
        for (int ni = 0; ni < 4; ++ni)
#pragma unroll
            for (int rr = 0; rr < 4; ++rr) {
                int row = m0 + wr + mi * 16 + quad * 4 + rr;
                int col = n0 + wc + ni * 16 + l16;
                pc[((size_t)dir * PP + row) * NPOOL + col] = f2b(acc[mi][ni][rr]);
            }
}

// ---------------- lookup: gather band (L0) + pooled-corr row (L1-3) ----------------
__global__ __launch_bounds__(384) void lookup(const u16* __restrict__ corr01,
                                              const u16* __restrict__ corr10,
                                              const u16* __restrict__ pc,
                                              u16* __restrict__ feat) {
    __shared__ __align__(16) u16 pcrow[NPOOL];
    int p = blockIdx.x, dir = blockIdx.y;
    int px = p % WW, py = p / WW;
    int tid = threadIdx.x;
    if (tid < NPOOL / 8)
        *(u16x8*)(&pcrow[tid * 8]) = *(const u16x8*)(&pc[((size_t)dir * PP + p) * NPOOL + tid * 8]);
    float l0v = 0.f;
    if (tid < 81) {
        int dx = tid / 9 - 4, dy = tid % 9 - 4;
        int x = px + dx, y = py + dy;
        if ((unsigned)x < (unsigned)WW && (unsigned)y < (unsigned)HH)
            l0v = b2f((dir ? corr10 : corr01)[(size_t)p * PP + y * WW + x]);
    }
    __syncthreads();
    int ch = tid;
    float val = 0.f;
    if (ch < CH) {
        int lvl = ch / 81, i = ch % 81;
        if (lvl == 0) {
            val = l0v;
        } else {
            int dx = i / 9 - 4, dy = i % 9 - 4;
            int wl = WW >> lvl;
            int base = (lvl == 1) ? 0 : (lvl == 2) ? 1600 : 2000;
            float inv = 1.0f / (float)(2 << lvl);
            float xc = (float)(2 * px + 1) * inv - 0.5f + (float)dx;
            float yc = (float)(2 * py + 1) * inv - 0.5f + (float)dy;
            float x0f = floorf(xc), y0f = floorf(yc);
            int x0 = (int)x0f, y0 = (int)y0f;
            float wx = xc - x0f, wy = yc - y0f;
#pragma unroll
            for (int cy = 0; cy < 2; ++cy)
#pragma unroll
                for (int cx = 0; cx < 2; ++cx) {
                    int xi = x0 + cx, yi = y0 + cy;
                    if ((unsigned)xi < (unsigned)wl && (unsigned)yi < (unsigned)wl) {
                        float wgt = (cx ? wx : 1.f - wx) * (cy ? wy : 1.f - wy);
                        val += b2f(pcrow[base + yi * wl + xi]) * wgt;
                    }
                }
        }
    }
    size_t pix = (size_t)(py + 1) * PW + px + 1;
    feat[((size_t)dir * PPIX + pix) * CPAD + ch] = f2b(val);
}

// ---------------- conv GEMM: patch-LDS A + register-dbuf weights from L2 ----------------
// Block = 128 px (8y x 16x) x 64 outch. Patch (10x18 px x 128ci, 45 KB) staged once per kt
// (6 barriers/block total). Weights loaded straight to VGPRs with distance-1 round prefetch
// (w0/w1 sets, statically indexed via paired rounds) - no LDS, no per-round barrier, and the
// prefetch->use distance is a full round (~32 MFMA + 16 ds_read > L2 latency).
#define LOADW(W, rnd) do {                                                         \
    int tap_ = (rnd) % 9, kt_ = (rnd) / 9;                                         \
    size_t off_ = (size_t)tap_ * CPAD * CPAD + kt_ * 128;                          \
    _Pragma("unroll")                                                              \
    for (int ni = 0; ni < 2; ++ni)                                                 \
        _Pragma("unroll")                                                          \
        for (int ki = 0; ki < 4; ++ki)                                             \
            W[ni * 4 + ki] = *(const bf16x8*)(wrow[ni] + off_ + ki * 32);          \
} while (0)

#define DOROUND(rnd, W) do {                                                       \
    int tap_ = (rnd) % 9;                                                          \
    int ty_ = tap_ / 3, tx_ = tap_ - ty_ * 3;                                      \
    _Pragma("unroll")                                                              \
    for (int ki = 0; ki < 4; ++ki) {                                               \
        bf16x8 af[4];                                                              \
        _Pragma("unroll")                                                          \
        for (int mi = 0; mi < 4; ++mi) {                                           \
            int r_ = wr + mi * 16 + l16;                                           \
            int pix_ = ((r_ >> 4) + ty_) * 18 + (r_ & 15) + tx_;                   \
            af[mi] = *(const bf16x8*)(&patchA[pix_ * 128 +                         \
                         (((ki * 4 + quad) ^ (pix_ & 15)) * 8)]);                  \
        }                                                                          \
        _Pragma("unroll")                                                          \
        for (int mi = 0; mi < 4; ++mi)                                             \
            _Pragma("unroll")                                                      \
            for (int ni = 0; ni < 2; ++ni)                                         \
                acc[mi][ni] = __builtin_amdgcn_mfma_f32_16x16x32_bf16(             \
                                  af[mi], W[ni * 4 + ki], acc[mi][ni], 0, 0, 0);   \
    }                                                                              \
} while (0)

__global__ __launch_bounds__(256) void conv_gemm(const u16* __restrict__ inFeat,
                                                 const u16* __restrict__ wTt,
                                                 const float* __restrict__ bias,
                                                 const u16* __restrict__ resid,
                                                 u16* __restrict__ outb) {
    int dir = blockIdx.z;
    const u16* Ain = inFeat + (size_t)dir * PPIX * CPAD;
    const u16* Rin = resid ? resid + (size_t)dir * PPIX * CPAD : (const u16*)0;
    u16* Out = outb + (size_t)dir * PPIX * CPAD;
    __shared__ __align__(16) u16 patchA[180 * 128];   // 45 KB: 10(y) x 18(x) px, 128-ci chunk
    int tid = threadIdx.x;
    int wave = tid >> 6, lane = tid & 63;
    int quad = lane >> 4, l16 = lane & 15;
    int lpx = lane >> 4, lch = lane & 15;             // staging: 4 rows x 16 chunks per issue
    int n0 = blockIdx.x * 64;
    int bm = (int)blockIdx.y;                         // 0..49
    int by = bm / 5, bx = bm % 5;                     // 10 x 5 tiles of 8(y) x 16(x) px
    int wr = (wave >> 1) * 64;                        // px half (y-rows 0..3 / 4..7)
    int wc = (wave & 1) * 32;                         // outch half
    int pbase = (by * 8) * PW + bx * 16;              // patch origin (incl. halo) in padded img
    f32x4 acc[4][2] = {};
    bf16x8 w0[8], w1[8];

    // wave-invariant weight row bases: co = n0 + wc + ni*16 + l16
    const u16* wrow[2];
#pragma unroll
    for (int ni = 0; ni < 2; ++ni)
        wrow[ni] = wTt + (size_t)(n0 + wc + ni * 16 + l16) * CPAD + quad * 8;

    auto stageP = [&](int kt) {
        for (int i = wave; i < 45; i += 4) {
            int pix = i * 4 + lpx;
            int iy = pix / 18, ix = pix - iy * 18;
            int gpix = pbase + iy * PW + ix;
            int sc = lch ^ (pix & 15);
            gload16(&Ain[(size_t)gpix * CPAD + kt * 128 + sc * 8], &patchA[(i * 4) * 128]);
        }
    };

    stageP(0);
    LOADW(w0, 0);
    __syncthreads();                                  // patch 0 ready
    for (int r2 = 0; r2 < 13; ++r2) {
        int rA = 2 * r2, rB = 2 * r2 + 1;
        LOADW(w1, rB);
        DOROUND(rA, w0);
        if (rA % 9 == 8) { __syncthreads(); stageP(rA / 9 + 1); __syncthreads(); }
        LOADW(w0, rB + 1);                            // rB+1 <= 26
        DOROUND(rB, w1);
        if (rB % 9 == 8) { __syncthreads(); stageP(rB / 9 + 1); __syncthreads(); }
    }
    DOROUND(26, w0);

#pragma unroll
    for (int mi = 0; mi < 4; ++mi)
#pragma unroll
        for (int rr = 0; rr < 4; ++rr) {
            int r = wr + mi * 16 + quad * 4 + rr;
            int yy = r >> 4, xx = r & 15;
            size_t opix = (size_t)(by * 8 + yy + 1) * PW + bx * 16 + xx + 1;
#pragma unroll
            for (int ni = 0; ni < 2; ++ni) {
                int co = n0 + wc + ni * 16 + l16;
                float v = acc[mi][ni][rr] + bias[co];
                v = fmaxf(v, 0.f);
                if (Rin) v += b2f(Rin[opix * CPAD + co]);
                Out[opix * CPAD + co] = f2b(v);
            }
        }
}

// ---------------- layernorm + transposed (channel-major) output ----------------
__global__ __launch_bounds__(256) void ln_out(const u16* __restrict__ t2,
                                              const float* __restrict__ g,
                                              const float* __restrict__ b,
                                              float* __restrict__ out) {
    int dir = blockIdx.y;
    int p0 = blockIdx.x * 64;
    const u16* Y = t2 + (size_t)dir * PPIX * CPAD;
    __shared__ u16 buf[64 * 325];
    __shared__ float mean_s[64], inv_s[64];
    __shared__ float part[64][4][2];
    int tid = threadIdx.x;
    for (int idx = tid; idx < 64 * CH; idx += 256) {
        int pp = idx / CH, c = idx - pp * CH;
        int p = p0 + pp;
        size_t pix = (size_t)(p / 80 + 1) * PW + (p % 80) + 1;
        buf[pp * 325 + c] = Y[pix * CPAD + c];
    }
    __syncthreads();
    {
        int pp = tid >> 2, q = tid & 3;
        float s = 0.f, s2 = 0.f;
        for (int c = q; c < CH; c += 4) { float v = b2f(buf[pp * 325 + c]); s += v; s2 += v * v; }
        part[pp][q][0] = s; part[pp][q][1] = s2;
    }
    __syncthreads();
    if (tid < 64) {
        float s = 0.f, s2 = 0.f;
        for (int q = 0; q < 4; ++q) { s += part[tid][q][0]; s2 += part[tid][q][1]; }
        float m = s / (float)CH;
        float var = s2 / (float)CH - m * m;
        if (var < 0.f) var = 0.f;
        mean_s[tid] = m;
        inv_s[tid] = rsqrtf(var + 1e-5f);
    }
    __syncthreads();
    for (int idx = tid; idx < CH * 64; idx += 256) {
        int c = idx >> 6, pp = idx & 63;
        float v = (b2f(buf[pp * 325 + c]) - mean_s[pp]) * inv_s[pp] * g[c] + b[c];
        out[((size_t)(dir * CH + c)) * PP + p0 + pp] = v;
    }
}

extern "C" void kernel_launch(void* const* d_in, const int* in_sizes, int n_in,
                              void* d_out, int out_size, void* d_ws, size_t ws_size,
                              hipStream_t stream) {
    const float* f0  = (const float*)d_in[0];
    const float* f1  = (const float*)d_in[1];
    const float* w1  = (const float*)d_in[2];
    const float* b1  = (const float*)d_in[3];
    const float* w2  = (const float*)d_in[4];
    const float* b2  = (const float*)d_in[5];
    const float* lng = (const float*)d_in[6];
    const float* lnb = (const float*)d_in[7];
    float* out = (float*)d_out;

    char* ws = (char*)d_ws;
    size_t off = 0;
    auto alloc = [&](size_t bytes) -> char* {
        char* r = ws + off;
        off += (bytes + 511) & ~(size_t)511;
        return r;
    };
    u16* fA     = (u16*)alloc((size_t)PP * KC * 2);
    u16* fB     = (u16*)alloc((size_t)PP * KC * 2);
    u16* corr01 = (u16*)alloc((size_t)PP * PP * 2);    // band region only written
    u16* corr10 = (u16*)alloc((size_t)PP * PP * 2);
    u16* pc     = (u16*)alloc((size_t)2 * PP * NPOOL * 2);
    u16* feat   = (u16*)alloc((size_t)2 * PPIX * CPAD * 2);
    u16* t1     = (u16*)alloc((size_t)2 * PPIX * CPAD * 2);
    u16* t2     = (u16*)alloc((size_t)2 * PPIX * CPAD * 2);
    u16* pbarA  = (u16*)alloc((size_t)NPOOL * KC * 2);
    u16* pbarB  = (u16*)alloc((size_t)NPOOL * KC * 2);
    u16* wT1    = (u16*)alloc((size_t)9 * CPAD * CPAD * 2);
    u16* wT2    = (u16*)alloc((size_t)9 * CPAD * CPAD * 2);
    float* b1p  = (float*)alloc(CPAD * 4);
    float* b2p  = (float*)alloc(CPAD * 4);

    prep_f<<<dim3(100, 4, 2), 256, 0, stream>>>(f0, f1, fA, fB);
    prep_w<<<dim3(9, 36, 2), 256, 0, stream>>>(w1, w2, wT1, wT2);
    prep_b<<<1, 384, 0, stream>>>(b1, b2, b1p, b2p);
    zero_border<<<dim3(324, 2), 384, 0, stream>>>(feat, t1);
    pool_feat<<<dim3(100, 2), 256, 0, stream>>>(fA, fB, pbarA, pbarB);
    gemm_band<<<dim3(50, 7), 256, 0, stream>>>(fA, fB, corr01, corr10);
    gemm_pool<<<dim3(50, 17, 2), 256, 0, stream>>>(fA, fB, pbarA, pbarB, pc);
    lookup<<<dim3(PP, 2), 384, 0, stream>>>(corr01, corr10, pc, feat);
    conv_gemm<<<dim3(6, 50, 2), 256, 0, stream>>>(feat, wT1, b1p, (const u16*)0, t1);
    conv_gemm<<<dim3(6, 50, 2), 256, 0, stream>>>(t1, wT2, b2p, feat, t2);
    ln_out<<<dim3(100, 2), 256, 0, stream>>>(t2, lng, lnb, out);
}

// Round 11
// 276.882 us; speedup vs baseline: 1.2648x; 1.2648x over previous
//
#include <hip/hip_runtime.h>

typedef unsigned short u16;
typedef unsigned int   u32;
typedef float f32x4 __attribute__((ext_vector_type(4)));
typedef __bf16 bf16x8 __attribute__((ext_vector_type(8)));
typedef unsigned short u16x8 __attribute__((ext_vector_type(8)));

#define PP   6400
#define HH   80
#define WW   80
#define KC   256
#define CH   324
#define CPAD 384
#define PW   82          // padded spatial width
#define PPIX (PW*PW)     // 6724 padded pixels
#define NPOOL 2176       // pooled cells padded (1600+400+100 -> 2176)

__device__ inline float b2f(u16 u) { union { u32 i; float f; } v; v.i = ((u32)u) << 16; return v.f; }
__device__ inline u16 f2b(float f) {
    union { u32 i; float f; } v; v.f = f;
    u32 r = v.i + 0x7fffu + ((v.i >> 16) & 1u);
    return (u16)(r >> 16);
}

// async global->LDS, 16B per lane; LDS dst = wave-uniform base + lane*16
__device__ __forceinline__ void gload16(const void* g, void* l) {
    __builtin_amdgcn_global_load_lds((const __attribute__((address_space(1))) void*)g,
                                     (__attribute__((address_space(3))) void*)l, 16, 0, 0);
}

// ---------------- prep: fA[p][c] = bf16(f[c][p]) via LDS tile transpose ----------------
__global__ __launch_bounds__(256) void prep_f(const float* __restrict__ f0,
                                              const float* __restrict__ f1,
                                              u16* __restrict__ fA, u16* __restrict__ fB) {
    __shared__ float tile[64][65];
    int p0 = blockIdx.x * 64, c0 = blockIdx.y * 64;
    const float* src = blockIdx.z ? f1 : f0;
    u16* dst = blockIdx.z ? fB : fA;
    int tid = threadIdx.x;
#pragma unroll
    for (int it = 0; it < 16; ++it) {
        int idx = tid + it * 256;
        int cc = idx >> 6, pp = idx & 63;
        tile[cc][pp] = src[(size_t)(c0 + cc) * PP + p0 + pp];
    }
    __syncthreads();
#pragma unroll
    for (int it = 0; it < 16; ++it) {
        int idx = tid + it * 256;
        int pp = idx >> 6, cc = idx & 63;
        dst[(size_t)(p0 + pp) * KC + c0 + cc] = f2b(tile[cc][pp]);
    }
}

// ---------------- prep weights (coalesced tile transpose): wT[tap][co][ci] ----------------
__global__ __launch_bounds__(256) void prep_w(const float* __restrict__ w1,
                                              const float* __restrict__ w2,
                                              u16* __restrict__ wT1, u16* __restrict__ wT2) {
    __shared__ float tile[64][65];
    int tap = blockIdx.x;                 // 0..8
    int t6 = blockIdx.y;                  // 0..35
    int ci0 = (t6 / 6) * 64, co0 = (t6 % 6) * 64;
    const float* w = blockIdx.z ? w2 : w1;
    u16* wT = blockIdx.z ? wT2 : wT1;
    int tid = threadIdx.x;
#pragma unroll
    for (int it = 0; it < 16; ++it) {
        int idx = tid + it * 256;
        int ciL = idx >> 6, coL = idx & 63;
        int ci = ci0 + ciL, co = co0 + coL;
        tile[ciL][coL] = (ci < CH && co < CH) ? w[((size_t)tap * CH + ci) * CH + co] : 0.f;
    }
    __syncthreads();
#pragma unroll
    for (int it = 0; it < 16; ++it) {
        int idx = tid + it * 256;
        int coL = idx >> 6, ciL = idx & 63;
        wT[((size_t)tap * CPAD + co0 + coL) * CPAD + ci0 + ciL] = f2b(tile[ciL][coL]);
    }
}

__global__ __launch_bounds__(384) void prep_b(const float* __restrict__ b1,
                                              const float* __restrict__ b2,
                                              float* __restrict__ b1p, float* __restrict__ b2p) {
    int t = threadIdx.x;
    b1p[t] = t < CH ? b1[t] : 0.f;
    b2p[t] = t < CH ? b2[t] : 0.f;
}

// ---------------- zero the 1-pixel halo of feat and t1 (ws is re-poisoned every call) ----------------
__global__ __launch_bounds__(384) void zero_border(u16* __restrict__ feat, u16* __restrict__ t1) {
    int bi = blockIdx.x, dir = blockIdx.y;
    int pix;
    if (bi < 82) pix = bi;                        // top row
    else if (bi < 164) pix = 81 * PW + (bi - 82); // bottom row
    else if (bi < 244) pix = (bi - 164 + 1) * PW; // left col
    else pix = (bi - 244 + 1) * PW + 81;          // right col
    size_t off = ((size_t)dir * PPIX + pix) * CPAD + threadIdx.x;
    feat[off] = 0;
    t1[off] = 0;
}

// ---------------- pooled features, hierarchical: L1(1600)+L2(400)+L3(100) in one pass ----------------
__global__ __launch_bounds__(256) void pool_feat(const u16* __restrict__ fA,
                                                 const u16* __restrict__ fB,
                                                 u16* __restrict__ pbarA,
                                                 u16* __restrict__ pbarB) {
    int j = blockIdx.x;                       // L3 cell 0..99
    const u16* src = blockIdx.y ? fA : fB;    // y=0: pooled B (for dir0), y=1: pooled A (for dir1)
    u16* dst = blockIdx.y ? pbarA : pbarB;
    int k = threadIdx.x;
    int cy3 = j / 10, cx3 = j % 10;
    float l1v[16], l2v[4];
#pragma unroll
    for (int a = 0; a < 4; ++a)
#pragma unroll
        for (int b = 0; b < 4; ++b) {
            int cy = cy3 * 4 + a, cx = cx3 * 4 + b;
            int p00 = (2 * cy) * 80 + 2 * cx;
            float v = 0.25f * (b2f(src[(size_t)p00 * KC + k]) + b2f(src[(size_t)(p00 + 1) * KC + k]) +
                               b2f(src[(size_t)(p00 + 80) * KC + k]) + b2f(src[(size_t)(p00 + 81) * KC + k]));
            l1v[a * 4 + b] = v;
            dst[(size_t)(cy * 40 + cx) * KC + k] = f2b(v);
        }
#pragma unroll
    for (int a = 0; a < 2; ++a)
#pragma unroll
        for (int b = 0; b < 2; ++b) {
            float v = 0.25f * (l1v[(2 * a) * 4 + 2 * b] + l1v[(2 * a) * 4 + 2 * b + 1] +
                               l1v[(2 * a + 1) * 4 + 2 * b] + l1v[(2 * a + 1) * 4 + 2 * b + 1]);
            l2v[a * 2 + b] = v;
            dst[(size_t)(1600 + (cy3 * 2 + a) * 20 + cx3 * 2 + b) * KC + k] = f2b(v);
        }
    float v3 = 0.25f * (l2v[0] + l2v[1] + l2v[2] + l2v[3]);
    dst[(size_t)(2000 + j) * KC + k] = f2b(v3);
}

// ---------------- merged GEMM: banded corr (y<7) + pooled-corr (y>=7), identical K-loop ----------------
__global__ __launch_bounds__(256) void gemm_cp(const u16* __restrict__ fA,
                                               const u16* __restrict__ fB,
                                               const u16* __restrict__ pbarA,
                                               const u16* __restrict__ pbarB,
                                               u16* __restrict__ corr01,
                                               u16* __restrict__ corr10,
                                               u16* __restrict__ pc) {
    int y = blockIdx.y, z = blockIdx.z;
    bool band = (y < 7);
    int m0 = blockIdx.x * 128, n0;
    const u16 *Aptr, *Bptr;
    if (band) {
        if (z) return;
        int n0t = (int)blockIdx.x + y - 3;
        if (n0t < 0 || n0t >= 50) return;
        n0 = n0t * 128;
        Aptr = fA; Bptr = fB;
    } else {
        n0 = (y - 7) * 128;
        Aptr = z ? fB : fA;
        Bptr = z ? pbarA : pbarB;
    }
    __shared__ __align__(16) char smem[128 * 136 * 2];   // As+Bs (32KB) overlap trans (34KB)
    u16* As = (u16*)smem;
    u16* Bs = As + 128 * 64;
    u16* trans = (u16*)smem;
    const int TS = 136;
    int tid = threadIdx.x;
    int wave = tid >> 6, lane = tid & 63;
    int quad = lane >> 4, l16 = lane & 15;
    int lrow = lane >> 3, lchunk = lane & 7;
    int sc = lchunk ^ (lrow & 7);
    int sw = l16 & 7;
    int wr = (wave >> 1) * 64, wc = (wave & 1) * 64;
    f32x4 acc[4][4] = {};

    for (int k0 = 0; k0 < KC; k0 += 64) {
        __syncthreads();
#pragma unroll
        for (int i = 0; i < 4; ++i) {
            int row = i * 32 + wave * 8 + lrow;
            gload16(&Aptr[(size_t)(m0 + row) * KC + k0 + sc * 8], &As[(i * 32 + wave * 8) * 64]);
            gload16(&Bptr[(size_t)(n0 + row) * KC + k0 + sc * 8], &Bs[(i * 32 + wave * 8) * 64]);
        }
        __syncthreads();
#pragma unroll
        for (int ki = 0; ki < 2; ++ki) {
            bf16x8 af[4], bfr[4];
#pragma unroll
            for (int mi = 0; mi < 4; ++mi) {
                int r = wr + mi * 16 + l16;
                af[mi] = *(const bf16x8*)(&As[r * 64 + (((ki * 4 + quad) ^ sw) * 8)]);
            }
#pragma unroll
            for (int ni = 0; ni < 4; ++ni) {
                int r = wc + ni * 16 + l16;
                bfr[ni] = *(const bf16x8*)(&Bs[r * 64 + (((ki * 4 + quad) ^ sw) * 8)]);
            }
#pragma unroll
            for (int mi = 0; mi < 4; ++mi)
#pragma unroll
                for (int ni = 0; ni < 4; ++ni)
                    acc[mi][ni] = __builtin_amdgcn_mfma_f32_16x16x32_bf16(af[mi], bfr[ni], acc[mi][ni], 0, 0, 0);
        }
    }
    if (!band) {
        int dir = z;
#pragma unroll
        for (int mi = 0; mi < 4; ++mi)
#pragma unroll
            for (int ni = 0; ni < 4; ++ni)
#pragma unroll
                for (int rr = 0; rr < 4; ++rr) {
                    int row = m0 + wr + mi * 16 + quad * 4 + rr;
                    int col = n0 + wc + ni * 16 + l16;
                    pc[((size_t)dir * PP + row) * NPOOL + col] = f2b(acc[mi][ni][rr]);
                }
        return;
    }
    // band epilogue: corr01 direct + corr10 = tile^T via LDS
#pragma unroll
    for (int mi = 0; mi < 4; ++mi)
#pragma unroll
        for (int ni = 0; ni < 4; ++ni)
#pragma unroll
            for (int rr = 0; rr < 4; ++rr) {
                int row = m0 + wr + mi * 16 + quad * 4 + rr;
                int col = n0 + wc + ni * 16 + l16;
                corr01[(size_t)row * PP + col] = f2b(acc[mi][ni][rr]);
            }
    __syncthreads();
#pragma unroll
    for (int mi = 0; mi < 4; ++mi)
#pragma unroll
        for (int ni = 0; ni < 4; ++ni) {
            int c = wc + ni * 16 + l16;
            int rbase = wr + mi * 16 + quad * 4;
#pragma unroll
            for (int h = 0; h < 2; ++h) {
                u32 pk = (u32)f2b(acc[mi][ni][2 * h]) | ((u32)f2b(acc[mi][ni][2 * h + 1]) << 16);
                *(u32*)(&trans[c * TS + rbase + 2 * h]) = pk;
            }
        }
    __syncthreads();
#pragma unroll
    for (int it = 0; it < 8; ++it) {
        int c = it * 16 + (tid >> 4);
        int r8 = (tid & 15) * 8;
        u16x8 v = *(const u16x8*)(&trans[c * TS + r8]);
        *(u16x8*)(&corr10[(size_t)(n0 + c) * PP + m0 + r8]) = v;
    }
}

// ---------------- lookup: 4 pixels per block; band (L0) + pooled-corr rows (L1-3) ----------------
__global__ __launch_bounds__(384) void lookup(const u16* __restrict__ corr01,
                                              const u16* __restrict__ corr10,
                                              const u16* __restrict__ pc,
                                              u16* __restrict__ feat) {
    __shared__ __align__(16) u16 pcrow[4][NPOOL];   // 34.8 KB
    __shared__ float l0buf[4][81];
    int p0 = blockIdx.x * 4, dir = blockIdx.y;
    int tid = threadIdx.x;
    const u16* corr = dir ? corr10 : corr01;
    for (int i = tid; i < 4 * (NPOOL / 8); i += 384) {
        int j = i / (NPOOL / 8), cc = i % (NPOOL / 8);
        *(u16x8*)(&pcrow[j][cc * 8]) =
            *(const u16x8*)(&pc[((size_t)dir * PP + p0 + j) * NPOOL + cc * 8]);
    }
    if (tid < 324) {
        int j = tid / 81, i = tid % 81;
        int p = p0 + j;
        int px = p % WW, py = p / WW;
        int dx = i / 9 - 4, dy = i % 9 - 4;
        int x = px + dx, yy = py + dy;
        float v = 0.f;
        if ((unsigned)x < (unsigned)WW && (unsigned)yy < (unsigned)HH)
            v = b2f(corr[(size_t)p * PP + yy * WW + x]);
        l0buf[j][i] = v;
    }
    __syncthreads();
    int ch = tid;
#pragma unroll
    for (int j = 0; j < 4; ++j) {
        int p = p0 + j;
        int px = p % WW, py = p / WW;
        float val = 0.f;
        if (ch < CH) {
            int lvl = ch / 81, i = ch % 81;
            if (lvl == 0) {
                val = l0buf[j][i];
            } else {
                int dx = i / 9 - 4, dy = i % 9 - 4;
                int wl = WW >> lvl;
                int base = (lvl == 1) ? 0 : (lvl == 2) ? 1600 : 2000;
                float inv = 1.0f / (float)(2 << lvl);
                float xc = (float)(2 * px + 1) * inv - 0.5f + (float)dx;
                float yc = (float)(2 * py + 1) * inv - 0.5f + (float)dy;
                float x0f = floorf(xc), y0f = floorf(yc);
                int x0 = (int)x0f, y0 = (int)y0f;
                float wx = xc - x0f, wy = yc - y0f;
#pragma unroll
                for (int cy = 0; cy < 2; ++cy)
#pragma unroll
                    for (int cx = 0; cx < 2; ++cx) {
                        int xi = x0 + cx, yi = y0 + cy;
                        if ((unsigned)xi < (unsigned)wl && (unsigned)yi < (unsigned)wl) {
                            float wgt = (cx ? wx : 1.f - wx) * (cy ? wy : 1.f - wy);
                            val += b2f(pcrow[j][base + yi * wl + xi]) * wgt;
                        }
                    }
            }
        }
        size_t pix = (size_t)(py + 1) * PW + px + 1;
        feat[((size_t)dir * PPIX + pix) * CPAD + ch] = f2b(val);
    }
}

// ---------------- conv GEMM: R3 structure (64x128 tile, BK=128) + XCD-swizzled linear grid ----------------
// R3 measured 61 us, 0 LDS conflicts. Linear grid L = xcd + 8*(n + 3*(mg + 13*dir)):
// the 3 n-tiles sharing one m-tile's A-window land on the same XCD (blockIdx%8 heuristic).
__global__ __launch_bounds__(256) void conv_gemm(const u16* __restrict__ inFeat,
                                                 const u16* __restrict__ wTt,
                                                 const float* __restrict__ bias,
                                                 const u16* __restrict__ resid,
                                                 u16* __restrict__ outb) {
    int L = (int)blockIdx.x;
    int xcd = L & 7;
    int q = L >> 3;
    int n_t = q % 3; q /= 3;
    int mg = q % 13;
    int dir = q / 13;
    int m_t = mg * 8 + xcd;
    if (m_t >= 100) return;
    const u16* Ain = inFeat + (size_t)dir * PPIX * CPAD;
    const u16* Rin = resid ? resid + (size_t)dir * PPIX * CPAD : (const u16*)0;
    u16* Out = outb + (size_t)dir * PPIX * CPAD;
    __shared__ __align__(16) u16 As[64 * 128];    // 16KB
    __shared__ __align__(16) u16 Bs[128 * 128];   // 32KB
    int tid = threadIdx.x;
    int wave = tid >> 6, lane = tid & 63;
    int quad = lane >> 4, l16 = lane & 15;
    int wr = (wave >> 1) * 32, wc = (wave & 1) * 64;
    int m0 = m_t * 64, n0 = n_t * 128;
    f32x4 acc[2][4] = {};

    int pixA[4], scI[4];
#pragma unroll
    for (int i = 0; i < 4; ++i) {
        int r = wave * 16 + i * 4 + quad;
        int m = m0 + r;
        pixA[i] = (m / 80 + 1) * PW + (m % 80) + 1;
        scI[i] = l16 ^ ((i * 4 + quad) & 15);
    }

    for (int tap = 0; tap < 9; ++tap) {
        int dpix = (tap / 3 - 1) * PW + (tap % 3) - 1;
        const u16* Wt = wTt + ((size_t)tap * CPAD + n0) * CPAD;
#pragma unroll
        for (int kt = 0; kt < 3; ++kt) {
            int kc = kt * 128;
            __syncthreads();
#pragma unroll
            for (int i = 0; i < 4; ++i)
                gload16(&Ain[(size_t)(pixA[i] + dpix) * CPAD + kc + scI[i] * 8],
                        &As[(wave * 16 + i * 4) * 128]);
#pragma unroll
            for (int j = 0; j < 8; ++j) {
                int rb = wave * 32 + j * 4;
                gload16(&Wt[(size_t)(rb + quad) * CPAD + kc + scI[j & 3] * 8],
                        &Bs[rb * 128]);
            }
            __syncthreads();
#pragma unroll
            for (int ki = 0; ki < 4; ++ki) {
                int slot = (ki * 4 + quad) ^ l16;
                bf16x8 af[2], bfr[4];
#pragma unroll
                for (int mi = 0; mi < 2; ++mi)
                    af[mi] = *(const bf16x8*)(&As[(wr + mi * 16 + l16) * 128 + slot * 8]);
#pragma unroll
                for (int ni = 0; ni < 4; ++ni)
                    bfr[ni] = *(const bf16x8*)(&Bs[(wc + ni * 16 + l16) * 128 + slot * 8]);
#pragma unroll
                for (int mi = 0; mi < 2; ++mi)
#pragma unroll
                    for (int ni = 0; ni < 4; ++ni)
                        acc[mi][ni] = __builtin_amdgcn_mfma_f32_16x16x32_bf16(af[mi], bfr[ni], acc[mi][ni], 0, 0, 0);
            }
        }
    }
#pragma unroll
    for (int mi = 0; mi < 2; ++mi)
#pragma unroll
        for (int rr = 0; rr < 4; ++rr) {
            int p = m0 + wr + mi * 16 + quad * 4 + rr;
            size_t opix = (size_t)(p / 80 + 1) * PW + (p % 80) + 1;
#pragma unroll
            for (int ni = 0; ni < 4; ++ni) {
                int co = n0 + wc + ni * 16 + l16;
                float v = acc[mi][ni][rr] + bias[co];
                v = fmaxf(v, 0.f);
                if (Rin) v += b2f(Rin[opix * CPAD + co]);
                Out[opix * CPAD + co] = f2b(v);
            }
        }
}

// ---------------- layernorm + transposed (channel-major) output ----------------
__global__ __launch_bounds__(256) void ln_out(const u16* __restrict__ t2,
                                              const float* __restrict__ g,
                                              const float* __restrict__ b,
                                              float* __restrict__ out) {
    int dir = blockIdx.y;
    int p0 = blockIdx.x * 64;
    const u16* Y = t2 + (size_t)dir * PPIX * CPAD;
    __shared__ u16 buf[64 * 325];
    __shared__ float mean_s[64], inv_s[64];
    __shared__ float part[64][4][2];
    int tid = threadIdx.x;
    for (int idx = tid; idx < 64 * CH; idx += 256) {
        int pp = idx / CH, c = idx - pp * CH;
        int p = p0 + pp;
        size_t pix = (size_t)(p / 80 + 1) * PW + (p % 80) + 1;
        buf[pp * 325 + c] = Y[pix * CPAD + c];
    }
    __syncthreads();
    {
        int pp = tid >> 2, q = tid & 3;
        float s = 0.f, s2 = 0.f;
        for (int c = q; c < CH; c += 4) { float v = b2f(buf[pp * 325 + c]); s += v; s2 += v * v; }
        part[pp][q][0] = s; part[pp][q][1] = s2;
    }
    __syncthreads();
    if (tid < 64) {
        float s = 0.f, s2 = 0.f;
        for (int q = 0; q < 4; ++q) { s += part[tid][q][0]; s2 += part[tid][q][1]; }
        float m = s / (float)CH;
        float var = s2 / (float)CH - m * m;
        if (var < 0.f) var = 0.f;
        mean_s[tid] = m;
        inv_s[tid] = rsqrtf(var + 1e-5f);
    }
    __syncthreads();
    for (int idx = tid; idx < CH * 64; idx += 256) {
        int c = idx >> 6, pp = idx & 63;
        float v = (b2f(buf[pp * 325 + c]) - mean_s[pp]) * inv_s[pp] * g[c] + b[c];
        out[((size_t)(dir * CH + c)) * PP + p0 + pp] = v;
    }
}

extern "C" void kernel_launch(void* const* d_in, const int* in_sizes, int n_in,
                              void* d_out, int out_size, void* d_ws, size_t ws_size,
                              hipStream_t stream) {
    const float* f0  = (const float*)d_in[0];
    const float* f1  = (const float*)d_in[1];
    const float* w1  = (const float*)d_in[2];
    const float* b1  = (const float*)d_in[3];
    const float* w2  = (const float*)d_in[4];
    const float* b2  = (const float*)d_in[5];
    const float* lng = (const float*)d_in[6];
    const float* lnb = (const float*)d_in[7];
    float* out = (float*)d_out;

    char* ws = (char*)d_ws;
    size_t off = 0;
    auto alloc = [&](size_t bytes) -> char* {
        char* r = ws + off;
        off += (bytes + 511) & ~(size_t)511;
        return r;
    };
    u16* fA     = (u16*)alloc((size_t)PP * KC * 2);
    u16* fB     = (u16*)alloc((size_t)PP * KC * 2);
    u16* corr01 = (u16*)alloc((size_t)PP * PP * 2);    // band region only written
    u16* corr10 = (u16*)alloc((size_t)PP * PP * 2);
    u16* pc     = (u16*)alloc((size_t)2 * PP * NPOOL * 2);
    u16* feat   = (u16*)alloc((size_t)2 * PPIX * CPAD * 2);
    u16* t1     = (u16*)alloc((size_t)2 * PPIX * CPAD * 2);
    u16* t2     = (u16*)alloc((size_t)2 * PPIX * CPAD * 2);
    u16* pbarA  = (u16*)alloc((size_t)NPOOL * KC * 2);
    u16* pbarB  = (u16*)alloc((size_t)NPOOL * KC * 2);
    u16* wT1    = (u16*)alloc((size_t)9 * CPAD * CPAD * 2);
    u16* wT2    = (u16*)alloc((size_t)9 * CPAD * CPAD * 2);
    float* b1p  = (float*)alloc(CPAD * 4);
    float* b2p  = (float*)alloc(CPAD * 4);

    prep_f<<<dim3(100, 4, 2), 256, 0, stream>>>(f0, f1, fA, fB);
    prep_w<<<dim3(9, 36, 2), 256, 0, stream>>>(w1, w2, wT1, wT2);
    prep_b<<<1, 384, 0, stream>>>(b1, b2, b1p, b2p);
    zero_border<<<dim3(324, 2), 384, 0, stream>>>(feat, t1);
    pool_feat<<<dim3(100, 2), 256, 0, stream>>>(fA, fB, pbarA, pbarB);
    gemm_cp<<<dim3(50, 24, 2), 256, 0, stream>>>(fA, fB, pbarA, pbarB, corr01, corr10, pc);
    lookup<<<dim3(1600, 2), 384, 0, stream>>>(corr01, corr10, pc, feat);
    conv_gemm<<<dim3(624), 256, 0, stream>>>(feat, wT1, b1p, (const u16*)0, t1);
    conv_gemm<<<dim3(624), 256, 0, stream>>>(t1, wT2, b2p, feat, t2);
    ln_out<<<dim3(100, 2), 256, 0, stream>>>(t2, lng, lnb, out);
}